// Round 3
// baseline (115.705 us; speedup 1.0000x reference)
//
#include <hip/hip_runtime.h>

#define NSEQ   24
#define NBOX   196
#define NCTX   196
#define MAXLEN 6
#define EPSV   1e-6f
#define BS     32

#define TILES      25    // i-tiles per batch, 8 waves/block -> 200 >= 196
#define K1_THREADS 512
#define NB4        (NBOX / 4)   // 49 float4 per row

// ws layout: araw[2][BS][NBOX], old_row[2][BS][NBOX]  (~100 KB)
#define WS_ARAW(buf)  ((buf) * BS * NBOX)
#define WS_OLD(buf)   ((2 + (buf)) * BS * NBOX)

// One kernel per traversal step. Fuses:
//  - step-0 ent->ea copy
//  - redundant per-block recompute of the PREVIOUS step's finalize (tile0 commits)
//  - staging of child rows (*kcls) into LDS
//  - the gather-dot over children -> add_raw for THIS step
__global__ __launch_bounds__(K1_THREADS) void step_fused(
    const float* __restrict__ ent,      // [BS,NSEQ,NBOX] original attn
    float*       __restrict__ ea,       // [BS,NSEQ,NBOX] state (d_out)
    const float* __restrict__ spo,      // [BS,NSEQ,NBOX,NCTX]
    const int*   __restrict__ ctx,      // [BS,NBOX,NCTX]
    const int*   __restrict__ roi_cls,  // [BS,NBOX]
    const float* __restrict__ rm,       // [BS,NBOX,NCTX]
    const float* __restrict__ wc,       // [BS,NSEQ,NBOX]
    const int*   __restrict__ trav,     // [BS,MAXLEN]
    const int*   __restrict__ adj,      // [BS,NSEQ,NSEQ]
    float*       __restrict__ ws,       // scratch, layout above
    int step)
{
    const int b    = blockIdx.x / TILES;
    const int tile = blockIdx.x % TILES;
    const int tid  = threadIdx.x;
    const float* state = (step == 0) ? ent : ea;

    float*       araw_w = ws + WS_ARAW(step & 1);
    const float* araw_r = ws + WS_ARAW((step ^ 1) & 1);
    float*       old_w  = ws + WS_OLD(step & 1);
    const float* old_r  = ws + WS_OLD((step ^ 1) & 1);

    __shared__ __align__(16) float cae[NSEQ][NBOX];  // child rows * kcls
    __shared__ __align__(16) float s_fin[NBOX];      // recomputed prev finalize
    __shared__ float s_upd[NBOX];
    __shared__ float s_red[8];
    __shared__ int   s_childE[NSEQ + 3];
    __shared__ int   s_childJ[NSEQ];
    __shared__ int   s_scal[5];  // nch, p, p_prev, nch_prev, use_fin

    // ---- fused ent -> ea copy (step 0 only; nothing reads ea this step)
    if (step == 0) {
        const int total4 = BS * NSEQ * NBOX / 4;
        int idx = blockIdx.x * K1_THREADS + tid;
        if (idx < total4) ((float4*)ea)[idx] = ((const float4*)ent)[idx];
    }

    // ---- parse adjacency for current and previous step
    if (tid == 0) {
        const int p = trav[b * MAXLEN + step];
        int n = 0;
        if (p >= 0) {
            const int* arow = adj + ((size_t)b * NSEQ + p) * NSEQ;
            for (int j = 0; j < NSEQ; ++j) {
                int e = arow[j];
                if (e >= 0) { s_childJ[n] = j; s_childE[n] = e; ++n; }
            }
        }
        int c0 = (n > 0) ? s_childE[0] : 0;
        s_childE[n] = c0; s_childE[n + 1] = c0; s_childE[n + 2] = c0;  // prefetch pad
        int pp = -1, np = 0;
        if (step > 0) {
            pp = trav[b * MAXLEN + step - 1];
            if (pp >= 0) {
                const int* arow = adj + ((size_t)b * NSEQ + pp) * NSEQ;
                for (int j = 0; j < NSEQ; ++j) np += (arow[j] >= 0) ? 1 : 0;
            }
        }
        s_scal[0] = n; s_scal[1] = p; s_scal[2] = pp; s_scal[3] = np;
        s_scal[4] = (step > 0 && pp >= 0 && np > 0) ? 1 : 0;
    }
    __syncthreads();
    const int nch = s_scal[0], p = s_scal[1], p_prev = s_scal[2],
              nch_prev = s_scal[3], use_fin = s_scal[4];

    // ---- recompute previous step's finalize (identical in every block of b)
    float a = 0.0f;
    if (use_fin && tid < NBOX) {
        float old = old_r[b * NBOX + tid];
        float w   = wc[((size_t)b * NSEQ + p_prev) * NBOX + tid];
        float u   = old + (araw_r[b * NBOX + tid] + (float)nch_prev * EPSV) * w;
        s_upd[tid] = u;
        a = fabsf(u);
    }
    #pragma unroll
    for (int off = 32; off >= 1; off >>= 1) a = fmaxf(a, __shfl_down(a, off, 64));
    if ((tid & 63) == 0) s_red[tid >> 6] = a;
    __syncthreads();
    if (use_fin && tid < NBOX) {
        float norm = fmaxf(fmaxf(fmaxf(s_red[0], s_red[1]), fmaxf(s_red[2], s_red[3])),
                           fmaxf(fmaxf(s_red[4], s_red[5]), fmaxf(s_red[6], s_red[7])));
        norm = (norm <= 1.0f) ? 1.0f : norm;
        float v = s_upd[tid] / norm;
        if (roi_cls[b * NBOX + tid] == -1) v = -1.0f;
        s_fin[tid] = v;
    }
    __syncthreads();

    // ---- tile-0 housekeeping: commit prev row; snapshot current parent row
    if (tile == 0 && tid < NBOX) {
        if (use_fin) ea[((size_t)b * NSEQ + p_prev) * NBOX + tid] = s_fin[tid];
        if (p >= 0) {
            float v = (use_fin && p == p_prev)
                      ? s_fin[tid]
                      : state[((size_t)b * NSEQ + p) * NBOX + tid];
            old_w[b * NBOX + tid] = v;
        }
    }

    if (nch == 0) return;  // uniform per block; housekeeping stores already issued

    // ---- stage child rows * kcls into LDS (prev-finalized row from LDS, not global)
    {
        const int items = nch * NB4;
        const int4* roi4 = (const int4*)(roi_cls + b * NBOX);
        for (int t = tid; t < items; t += K1_THREADS) {
            int n = t / NB4, q = t - n * NB4;
            int j = s_childJ[n];
            float4 e4 = (use_fin && j == p_prev)
                        ? ((const float4*)s_fin)[q]
                        : ((const float4*)(state + ((size_t)b * NSEQ + j) * NBOX))[q];
            int4 r4 = roi4[q];
            float4 v;
            v.x = (r4.x != -1) ? e4.x : 0.0f;
            v.y = (r4.y != -1) ? e4.y : 0.0f;
            v.z = (r4.z != -1) ? e4.z : 0.0f;
            v.w = (r4.w != -1) ? e4.w : 0.0f;
            ((float4*)&cae[n][0])[q] = v;
        }
    }
    __syncthreads();

    // ---- gather-dot: one i per wave, 3-deep rotating spo prefetch
    const int wave = tid >> 6, lane = tid & 63;
    const int i = tile * 8 + wave;
    if (i >= NBOX) return;

    float acc = 0.0f;
    if (lane < NB4) {
        const size_t bi = (size_t)b * NBOX + i;
        const int4   idx4 = ((const int4*)  (ctx + bi * NCTX))[lane];
        const float4 m4   = ((const float4*)(rm  + bi * NCTX))[lane];
        const float* sb = spo + ((size_t)b * NSEQ * NBOX + i) * NCTX;
        const size_t stride = (size_t)NBOX * NCTX;

        float4 a4 = make_float4(0.f, 0.f, 0.f, 0.f);
        float4 s0 = ((const float4*)(sb + (size_t)s_childE[0] * stride))[lane];
        float4 s1 = ((const float4*)(sb + (size_t)s_childE[1] * stride))[lane];
        float4 s2 = ((const float4*)(sb + (size_t)s_childE[2] * stride))[lane];
        for (int n = 0; n < nch; ++n) {
            float4 nx = ((const float4*)(sb + (size_t)s_childE[n + 3] * stride))[lane];
            a4.x = fmaf(m4.x * cae[n][idx4.x], s0.x, a4.x);
            a4.y = fmaf(m4.y * cae[n][idx4.y], s0.y, a4.y);
            a4.z = fmaf(m4.z * cae[n][idx4.z], s0.z, a4.z);
            a4.w = fmaf(m4.w * cae[n][idx4.w], s0.w, a4.w);
            s0 = s1; s1 = s2; s2 = nx;
        }
        acc = (a4.x + a4.y) + (a4.z + a4.w);
    }
    #pragma unroll
    for (int off = 32; off >= 1; off >>= 1) acc += __shfl_down(acc, off, 64);
    if (lane == 0) {
        float kci = (roi_cls[b * NBOX + i] != -1) ? 1.0f : 0.0f;
        araw_w[b * NBOX + i] = kci * acc;
    }
}

// ---- finalize of the last traversal step
__global__ __launch_bounds__(256) void tail_finalize(
    float*       __restrict__ ea,
    const float* __restrict__ ws,       // read araw[last&1], old_row[last&1]
    const float* __restrict__ wc,
    const int*   __restrict__ roi_cls,
    const int*   __restrict__ trav,
    const int*   __restrict__ adj)
{
    const int b = blockIdx.x, tid = threadIdx.x;
    const int last = MAXLEN - 1;
    const float* araw = ws + WS_ARAW(last & 1);
    const float* oldr = ws + WS_OLD(last & 1);
    const int p = trav[b * MAXLEN + last];
    int nch = 0;
    if (p >= 0) {
        const int* ar = adj + ((size_t)b * NSEQ + p) * NSEQ;
        for (int j = 0; j < NSEQ; ++j) nch += (ar[j] >= 0) ? 1 : 0;
    }
    if (p < 0 || nch == 0) return;

    float upd = 0.0f, a = 0.0f;
    if (tid < NBOX) {
        float old = oldr[b * NBOX + tid];
        float w   = wc[((size_t)b * NSEQ + p) * NBOX + tid];
        upd = old + (araw[b * NBOX + tid] + (float)nch * EPSV) * w;
        a = fabsf(upd);
    }
    #pragma unroll
    for (int off = 32; off >= 1; off >>= 1) a = fmaxf(a, __shfl_down(a, off, 64));
    __shared__ float wmax[4];
    if ((tid & 63) == 0) wmax[tid >> 6] = a;
    __syncthreads();
    float norm = fmaxf(fmaxf(wmax[0], wmax[1]), fmaxf(wmax[2], wmax[3]));
    norm = (norm <= 1.0f) ? 1.0f : norm;
    if (tid < NBOX) {
        float val = upd / norm;
        if (roi_cls[b * NBOX + tid] == -1) val = -1.0f;
        ea[((size_t)b * NSEQ + p) * NBOX + tid] = val;
    }
}

extern "C" void kernel_launch(void* const* d_in, const int* in_sizes, int n_in,
                              void* d_out, int out_size, void* d_ws, size_t ws_size,
                              hipStream_t stream) {
    const int*   trav = (const int*)  d_in[0];
    const int*   adj  = (const int*)  d_in[1];
    const float* ent  = (const float*)d_in[2];
    const float* spo  = (const float*)d_in[3];
    const int*   ctx  = (const int*)  d_in[4];
    const int*   roi  = (const int*)  d_in[5];
    const float* rm   = (const float*)d_in[6];
    const float* wc   = (const float*)d_in[7];

    float* ea = (float*)d_out;
    float* ws = (float*)d_ws;   // 4 * BS * NBOX floats (~100 KB)

    for (int t = 0; t < MAXLEN; ++t) {
        step_fused<<<BS * TILES, K1_THREADS, 0, stream>>>(
            ent, ea, spo, ctx, roi, rm, wc, trav, adj, ws, t);
    }
    tail_finalize<<<BS, 256, 0, stream>>>(ea, ws, wc, roi, trav, adj);
}